// Round 1
// baseline (2126.455 us; speedup 1.0000x reference)
//
#include <hip/hip_runtime.h>

// MultiHeadAttention_26276609917518 — MI355X (gfx950)
// B=8, N=4096, DIM=2048, H=16, hd=128.
// Pipeline: cast->bf16, QKV GEMM (MFMA), per-token head-attention (+permute), proj GEMM.

typedef unsigned short u16;
typedef unsigned int   u32;
typedef __bf16  bf16x8  __attribute__((ext_vector_type(8)));
typedef float   floatx4 __attribute__((ext_vector_type(4)));

#define GAS __attribute__((address_space(1)))
#define LAS __attribute__((address_space(3)))

__device__ __forceinline__ u16 f2bf(float x) {
  u32 u = __builtin_bit_cast(u32, x);
  return (u16)((u + 0x7FFFu + ((u >> 16) & 1u)) >> 16);
}
__device__ __forceinline__ u32 f2bf2(float lo, float hi) {
  u32 a = __builtin_bit_cast(u32, lo);
  u32 b = __builtin_bit_cast(u32, hi);
  a = (a + 0x7FFFu + ((a >> 16) & 1u)) >> 16;
  b = (b + 0x7FFFu + ((b >> 16) & 1u)) >> 16;
  return a | (b << 16);
}
__device__ __forceinline__ float bf2f(u32 lo16) {
  return __builtin_bit_cast(float, lo16 << 16);
}
__device__ __forceinline__ void unpack8(uint4 r, float* f) {
  f[0] = bf2f(r.x & 0xffffu); f[1] = bf2f(r.x >> 16);
  f[2] = bf2f(r.y & 0xffffu); f[3] = bf2f(r.y >> 16);
  f[4] = bf2f(r.z & 0xffffu); f[5] = bf2f(r.z >> 16);
  f[6] = bf2f(r.w & 0xffffu); f[7] = bf2f(r.w >> 16);
}

// ---------------- cast fp32 -> bf16, 8 elems/thread ----------------
__global__ __launch_bounds__(256)
void cast_bf16_k(const float4* __restrict__ in, uint4* __restrict__ out, long n8) {
  long i = (long)blockIdx.x * 256 + threadIdx.x;
  if (i >= n8) return;
  float4 a = in[2 * i], b = in[2 * i + 1];
  uint4 o;
  o.x = f2bf2(a.x, a.y); o.y = f2bf2(a.z, a.w);
  o.z = f2bf2(b.x, b.y); o.w = f2bf2(b.z, b.w);
  out[i] = o;
}

// ---------------- C = A(MxK) @ B(NxK)^T, bf16 in, fp32 acc ----------------
// m97 structure: 128x128 tile, BK=32, 4 waves in 2x2, 4x4 mfma_16x16x32 per wave,
// global_load_lds width=16 (LDS layout contiguous in lane order, NO padding).
template<int OUT_BF16>
__global__ __launch_bounds__(256)
void gemm_bt_k(const u16* __restrict__ A, const u16* __restrict__ B,
               void* __restrict__ Cv, int N_, int K)
{
  __shared__ u16 lA[128 * 32];
  __shared__ u16 lB[128 * 32];

  const int t    = threadIdx.x;
  const int wave = t >> 6;
  const int lane = t & 63;
  const int wm = wave >> 1, wn = wave & 1;
  const int lrow = lane & 15, quad = lane >> 4;

  const long tileM = (long)blockIdx.y * 128;
  const long tileN = (long)blockIdx.x * 128;

  // staging: thread t covers 8 contiguous K-elems of row (t>>2); 256 thr = 64 rows/issue
  const int srow = t >> 2;
  const int scol = (t & 3) << 3;
  const u16* gA = A + (tileM + srow) * (long)K + scol;
  const u16* gB = B + (tileN + srow) * (long)K + scol;
  const long halfStride = 64L * K;

  // wave-uniform LDS destinations (lane*16B appended by HW)
  LAS u16* dA0 = (LAS u16*)(lA + wave * 512);
  LAS u16* dA1 = (LAS u16*)(lA + 2048 + wave * 512);
  LAS u16* dB0 = (LAS u16*)(lB + wave * 512);
  LAS u16* dB1 = (LAS u16*)(lB + 2048 + wave * 512);

  floatx4 acc[4][4] = {};

  for (int k0 = 0; k0 < K; k0 += 32) {
    __builtin_amdgcn_global_load_lds((GAS void*)(gA + k0),              (LAS void*)dA0, 16, 0, 0);
    __builtin_amdgcn_global_load_lds((GAS void*)(gA + halfStride + k0), (LAS void*)dA1, 16, 0, 0);
    __builtin_amdgcn_global_load_lds((GAS void*)(gB + k0),              (LAS void*)dB0, 16, 0, 0);
    __builtin_amdgcn_global_load_lds((GAS void*)(gB + halfStride + k0), (LAS void*)dB1, 16, 0, 0);
    __syncthreads();

    bf16x8 af[4], bfr[4];
#pragma unroll
    for (int i = 0; i < 4; ++i)
      af[i] = *(const bf16x8*)&lA[(wm * 64 + i * 16 + lrow) * 32 + quad * 8];
#pragma unroll
    for (int j = 0; j < 4; ++j)
      bfr[j] = *(const bf16x8*)&lB[(wn * 64 + j * 16 + lrow) * 32 + quad * 8];
#pragma unroll
    for (int i = 0; i < 4; ++i)
#pragma unroll
      for (int j = 0; j < 4; ++j)
        acc[i][j] = __builtin_amdgcn_mfma_f32_16x16x32_bf16(af[i], bfr[j], acc[i][j], 0, 0, 0);
    __syncthreads();
  }

  // C/D layout: col = lane&15, row = quad*4 + reg  (m89/m91 verified)
#pragma unroll
  for (int i = 0; i < 4; ++i) {
#pragma unroll
    for (int r = 0; r < 4; ++r) {
      const long row = tileM + wm * 64 + i * 16 + quad * 4 + r;
#pragma unroll
      for (int j = 0; j < 4; ++j) {
        const long col = tileN + wn * 64 + j * 16 + lrow;
        const float v = acc[i][j][r];
        if (OUT_BF16) ((u16*)Cv)[row * (long)N_ + col] = f2bf(v);
        else          ((float*)Cv)[row * (long)N_ + col] = v;
      }
    }
  }
}

// ---------------- per-token 16-head x 16-head attention + permute ----------------
// qkv row (token) layout: [q 16x128 | k 16x128 | v 16x128], bf16.
// Writes y[b*4096 + h*256 + (n>>4)][ (n&15)*128 + d ]  (the reference's transpose+reshape).
__global__ __launch_bounds__(256)
void attn_k(const u16* __restrict__ qkv, u16* __restrict__ y)
{
  __shared__ float sq[16 * 132];       // q rows padded +4 (bank-conflict break)
  __shared__ float skT[128 * 17];      // k transposed, padded
  __shared__ float sv[16 * 128];
  __shared__ float sS[16 * 17];
  __shared__ float sP[16 * 17];

  const int t = threadIdx.x;
  const int token = blockIdx.x;        // b*4096 + n
  const int n = token & 4095;
  const int b = token >> 12;
  const u16* base = qkv + (long)token * 6144;

  float f[8];
  { // q
    uint4 raw = *(const uint4*)(base + t * 8);
    unpack8(raw, f);
    float* dst = &sq[(t >> 4) * 132 + (t & 15) * 8];
    ((float4*)dst)[0] = make_float4(f[0], f[1], f[2], f[3]);
    ((float4*)dst)[1] = make_float4(f[4], f[5], f[6], f[7]);
  }
  { // k -> transposed
    uint4 raw = *(const uint4*)(base + 2048 + t * 8);
    unpack8(raw, f);
    const int j = t >> 4;
    const int d0 = (t & 15) * 8;
#pragma unroll
    for (int e = 0; e < 8; ++e) skT[(d0 + e) * 17 + j] = f[e];
  }
  { // v
    uint4 raw = *(const uint4*)(base + 4096 + t * 8);
    unpack8(raw, f);
    float* dst = &sv[t * 8];
    ((float4*)dst)[0] = make_float4(f[0], f[1], f[2], f[3]);
    ((float4*)dst)[1] = make_float4(f[4], f[5], f[6], f[7]);
  }
  __syncthreads();

  { // scores: thread (i = t>>4, j = t&15)
    const int i = t >> 4, j = t & 15;
    const float* qi = &sq[i * 132];
    float s = 0.f;
#pragma unroll 16
    for (int d = 0; d < 128; ++d) s += qi[d] * skT[d * 17 + j];
    sS[i * 17 + j] = s * 0.08838834764831845f;   // 1/sqrt(128)
  }
  __syncthreads();

  { // softmax over j (row stats recomputed by each of the 16 row-threads)
    const int i = t >> 4, j = t & 15;
    float mx = -1e30f;
#pragma unroll
    for (int jj = 0; jj < 16; ++jj) mx = fmaxf(mx, sS[i * 17 + jj]);
    float sum = 0.f;
#pragma unroll
    for (int jj = 0; jj < 16; ++jj) sum += __expf(sS[i * 17 + jj] - mx);
    sP[i * 17 + j] = __expf(sS[i * 17 + j] - mx) / sum;
  }
  __syncthreads();

  { // out: thread (i = t&15 [head], dblk = t>>4); conflict-free v broadcast reads
    const int i = t & 15, dblk = t >> 4;
    float o[8] = {};
#pragma unroll
    for (int jj = 0; jj < 16; ++jj) {
      const float p = sP[i * 17 + jj];
      const float* vv = &sv[jj * 128 + dblk * 8];
#pragma unroll
      for (int e = 0; e < 8; ++e) o[e] += p * vv[e];
    }
    const long row  = (long)b * 4096 + i * 256 + (n >> 4);
    const long colb = (long)(n & 15) * 128 + dblk * 8;
    uint4 pk;
    pk.x = f2bf2(o[0], o[1]); pk.y = f2bf2(o[2], o[3]);
    pk.z = f2bf2(o[4], o[5]); pk.w = f2bf2(o[6], o[7]);
    *(uint4*)&y[row * 2048 + colb] = pk;
  }
}

// ---------------- launch ----------------
extern "C" void kernel_launch(void* const* d_in, const int* in_sizes, int n_in,
                              void* d_out, int out_size, void* d_ws, size_t ws_size,
                              hipStream_t stream)
{
  const float* x      = (const float*)d_in[0];
  const float* w_qkv  = (const float*)d_in[1];
  const float* w_proj = (const float*)d_in[2];

  const long NX  = 67108864L;   // 8*4096*2048
  const long NWQ = 12582912L;   // 6144*2048
  const long NWP = 4194304L;    // 2048*2048
  const long NQKV = 32768L * 6144;
  const long NY   = 32768L * 2048;

  char* ws = (char*)d_ws;
  u16* xb   = (u16*)ws;  ws += NX * 2;
  u16* wqb  = (u16*)ws;  ws += NWQ * 2;
  u16* wpb  = (u16*)ws;  ws += NWP * 2;
  u16* qkvb = (u16*)ws;  ws += NQKV * 2;
  u16* yb   = (u16*)ws;  ws += NY * 2;
  // total = 704,643,072 bytes; if ws_size < this the bench will show poison-absmax.
  if (ws_size < (size_t)704643072L) return;  // diagnostic: absmax stays ~454

  cast_bf16_k<<<dim3((u32)(NX  / 2048)), 256, 0, stream>>>((const float4*)x,      (uint4*)xb,  NX  / 8);
  cast_bf16_k<<<dim3((u32)(NWQ / 2048)), 256, 0, stream>>>((const float4*)w_qkv,  (uint4*)wqb, NWQ / 8);
  cast_bf16_k<<<dim3((u32)(NWP / 2048)), 256, 0, stream>>>((const float4*)w_proj, (uint4*)wpb, NWP / 8);

  // qkv = x @ w_qkv^T : M=32768, N=6144, K=2048
  gemm_bt_k<1><<<dim3(48, 256), 256, 0, stream>>>(xb, wqb, (void*)qkvb, 6144, 2048);

  // head-attention + permute
  attn_k<<<dim3(32768), 256, 0, stream>>>(qkvb, yb);

  // out = y @ w_proj^T : M=32768, N=2048, K=2048, fp32 out
  gemm_bt_k<0><<<dim3(16, 256), 256, 0, stream>>>(yb, wpb, d_out, 2048, 2048);
}